// Round 2
// baseline (6193.436 us; speedup 1.0000x reference)
//
#include <hip/hip_runtime.h>
#include <math.h>

static constexpr float kSceneScale = 4.0f;
static constexpr int   kG          = 32;          // sort grid per axis
static constexpr int   kNBins      = kG * kG * kG + 1;  // +1 = "outside" bin

__device__ __forceinline__ void fma4(float4& acc, float w, const float4& c) {
    acc.x = fmaf(w, c.x, acc.x);
    acc.y = fmaf(w, c.y, acc.y);
    acc.z = fmaf(w, c.z, acc.z);
    acc.w = fmaf(w, c.w, acc.w);
}

template <int RES>
__device__ __forceinline__ void trilerp_acc(const float4* __restrict__ cb,
                                            float x, float y, float z,
                                            float4& acc) {
    const float s = (float)(RES - 1);
    float fx = x * s, fy = y * s, fz = z * s;
    int x0 = min((int)fx, RES - 2);
    int y0 = min((int)fy, RES - 2);
    int z0 = min((int)fz, RES - 2);
    float tx = fx - (float)x0;
    float ty = fy - (float)y0;
    float tz = fz - (float)z0;

    int base = (x0 * RES + y0) * RES + z0;

    float4 c000 = cb[base];
    float4 c001 = cb[base + 1];
    float4 c010 = cb[base + RES];
    float4 c011 = cb[base + RES + 1];
    float4 c100 = cb[base + RES * RES];
    float4 c101 = cb[base + RES * RES + 1];
    float4 c110 = cb[base + RES * RES + RES];
    float4 c111 = cb[base + RES * RES + RES + 1];

    float wx0 = 1.0f - tx, wx1 = tx;
    float wy0 = 1.0f - ty, wy1 = ty;
    float wz0 = 1.0f - tz, wz1 = tz;

    fma4(acc, wx0 * wy0 * wz0, c000);
    fma4(acc, wx0 * wy0 * wz1, c001);
    fma4(acc, wx0 * wy1 * wz0, c010);
    fma4(acc, wx0 * wy1 * wz1, c011);
    fma4(acc, wx1 * wy0 * wz0, c100);
    fma4(acc, wx1 * wy0 * wz1, c101);
    fma4(acc, wx1 * wy1 * wz0, c110);
    fma4(acc, wx1 * wy1 * wz1, c111);
}

__device__ __forceinline__ void load_p01(const float* __restrict__ pts, int i,
                                         float& x, float& y, float& z, bool& inside) {
    float px = pts[3 * i + 0] * (1.0f / kSceneScale);
    float py = pts[3 * i + 1] * (1.0f / kSceneScale);
    float pz = pts[3 * i + 2] * (1.0f / kSceneScale);
    inside = (fabsf(px) < 0.5f) && (fabsf(py) < 0.5f) && (fabsf(pz) < 0.5f);
    x = fminf(fmaxf(px + 0.5f, 0.0f), 1.0f);
    y = fminf(fmaxf(py + 0.5f, 0.0f), 1.0f);
    z = fminf(fmaxf(pz + 0.5f, 0.0f), 1.0f);
}

// ---------------- Pass A: keys + histogram ----------------
__global__ __launch_bounds__(256) void keys_hist_kernel(
        const float* __restrict__ pts, unsigned* __restrict__ keys,
        unsigned* __restrict__ hist, int n) {
    int i = blockIdx.x * blockDim.x + threadIdx.x;
    if (i >= n) return;
    float x, y, z; bool inside;
    load_p01(pts, i, x, y, z, inside);
    unsigned key;
    if (inside) {
        int bx = min((int)(x * kG), kG - 1);
        int by = min((int)(y * kG), kG - 1);
        int bz = min((int)(z * kG), kG - 1);
        key = (unsigned)((bx * kG + by) * kG + bz);
    } else {
        key = (unsigned)(kNBins - 1);
    }
    keys[i] = key;
    atomicAdd(&hist[key], 1u);
}

// ---------------- Pass B: exclusive scan (1 block, in place) ----------------
__global__ __launch_bounds__(1024) void scan_kernel(unsigned* __restrict__ hist, int nbins) {
    __shared__ unsigned tmp[1024];
    __shared__ unsigned carry_s;
    int tid = threadIdx.x;
    if (tid == 0) carry_s = 0;
    __syncthreads();
    for (int base = 0; base < nbins; base += 1024) {
        unsigned v = (base + tid < nbins) ? hist[base + tid] : 0u;
        tmp[tid] = v;
        __syncthreads();
        // Hillis-Steele inclusive scan
        for (int off = 1; off < 1024; off <<= 1) {
            unsigned t = (tid >= off) ? tmp[tid - off] : 0u;
            __syncthreads();
            tmp[tid] += t;
            __syncthreads();
        }
        unsigned incl = tmp[tid];
        unsigned carry = carry_s;
        if (base + tid < nbins) hist[base + tid] = carry + incl - v;  // exclusive
        __syncthreads();
        if (tid == 1023) carry_s = carry + incl;
        __syncthreads();
    }
}

// ---------------- Pass C: scatter sorted order ----------------
__global__ __launch_bounds__(256) void scatter_kernel(
        const unsigned* __restrict__ keys, unsigned* __restrict__ offs,
        unsigned* __restrict__ order, int n) {
    int i = blockIdx.x * blockDim.x + threadIdx.x;
    if (i >= n) return;
    unsigned pos = atomicAdd(&offs[keys[i]], 1u);
    order[pos] = (unsigned)i;
}

// ---------------- Pass D: gather + trilerp in sorted order ----------------
__global__ __launch_bounds__(256) void compute_kernel(
        const float* __restrict__ pts,
        const unsigned* __restrict__ order,
        const float4* __restrict__ cb0,
        const float4* __restrict__ cb1,
        const float4* __restrict__ cb2,
        const float4* __restrict__ cb3,
        const float4* __restrict__ cb4,
        float* __restrict__ out,
        int n) {
    int t = blockIdx.x * blockDim.x + threadIdx.x;
    if (t >= n) return;
    int i = (int)order[t];

    float x, y, z; bool inside;
    load_p01(pts, i, x, y, z, inside);

    float c0 = 0.0f, c1 = 0.0f, c2 = 0.0f, sg = 0.0f;
    if (inside) {
        float4 acc = make_float4(0.0f, 0.0f, 0.0f, 0.0f);
        trilerp_acc<16>(cb0, x, y, z, acc);
        trilerp_acc<32>(cb1, x, y, z, acc);
        trilerp_acc<64>(cb2, x, y, z, acc);
        trilerp_acc<128>(cb3, x, y, z, acc);
        trilerp_acc<256>(cb4, x, y, z, acc);
        c0 = acc.x; c1 = acc.y; c2 = acc.z; sg = expf(acc.w);
    }

    out[3 * i + 0] = c0;
    out[3 * i + 1] = c1;
    out[3 * i + 2] = c2;
    out[(size_t)3 * n + i] = sg;
}

// ---------------- Fallback: direct (round-0) kernel ----------------
__global__ __launch_bounds__(256) void direct_kernel(
        const float* __restrict__ pts,
        const float4* __restrict__ cb0,
        const float4* __restrict__ cb1,
        const float4* __restrict__ cb2,
        const float4* __restrict__ cb3,
        const float4* __restrict__ cb4,
        float* __restrict__ out,
        int n) {
    int i = blockIdx.x * blockDim.x + threadIdx.x;
    if (i >= n) return;
    float x, y, z; bool inside;
    load_p01(pts, i, x, y, z, inside);
    float c0 = 0.0f, c1 = 0.0f, c2 = 0.0f, sg = 0.0f;
    if (inside) {
        float4 acc = make_float4(0.0f, 0.0f, 0.0f, 0.0f);
        trilerp_acc<16>(cb0, x, y, z, acc);
        trilerp_acc<32>(cb1, x, y, z, acc);
        trilerp_acc<64>(cb2, x, y, z, acc);
        trilerp_acc<128>(cb3, x, y, z, acc);
        trilerp_acc<256>(cb4, x, y, z, acc);
        c0 = acc.x; c1 = acc.y; c2 = acc.z; sg = expf(acc.w);
    }
    out[3 * i + 0] = c0;
    out[3 * i + 1] = c1;
    out[3 * i + 2] = c2;
    out[(size_t)3 * n + i] = sg;
}

extern "C" void kernel_launch(void* const* d_in, const int* in_sizes, int n_in,
                              void* d_out, int out_size, void* d_ws, size_t ws_size,
                              hipStream_t stream) {
    const float* pts = (const float*)d_in[0];
    const float4* cb0 = (const float4*)d_in[2];
    const float4* cb1 = (const float4*)d_in[3];
    const float4* cb2 = (const float4*)d_in[4];
    const float4* cb3 = (const float4*)d_in[5];
    const float4* cb4 = (const float4*)d_in[6];
    float* out = (float*)d_out;

    int n = in_sizes[0] / 3;

    size_t need = (size_t)2 * n * sizeof(unsigned) + (size_t)kNBins * sizeof(unsigned);
    dim3 block(256);
    dim3 grid((n + 255) / 256);

    if (ws_size < need) {
        direct_kernel<<<grid, block, 0, stream>>>(pts, cb0, cb1, cb2, cb3, cb4, out, n);
        return;
    }

    unsigned* keys  = (unsigned*)d_ws;
    unsigned* order = keys + n;
    unsigned* hist  = order + n;

    hipMemsetAsync(hist, 0, (size_t)kNBins * sizeof(unsigned), stream);
    keys_hist_kernel<<<grid, block, 0, stream>>>(pts, keys, hist, n);
    scan_kernel<<<1, 1024, 0, stream>>>(hist, kNBins);
    scatter_kernel<<<grid, block, 0, stream>>>(keys, hist, order, n);
    compute_kernel<<<grid, block, 0, stream>>>(pts, order, cb0, cb1, cb2, cb3, cb4, out, n);
}

// Round 3
// 288.124 us; speedup vs baseline: 21.4957x; 21.4957x over previous
//
#include <hip/hip_runtime.h>
#include <math.h>

static constexpr float kSceneScale = 4.0f;
static constexpr int   kG     = 16;                 // sort grid per axis
static constexpr int   kNBins = kG * kG * kG + 1;   // 4097, +1 = "outside"
static constexpr int   kNB    = 256;                // histogram blocks

__device__ __forceinline__ void fma4(float4& acc, float w, const float4& c) {
    acc.x = fmaf(w, c.x, acc.x);
    acc.y = fmaf(w, c.y, acc.y);
    acc.z = fmaf(w, c.z, acc.z);
    acc.w = fmaf(w, c.w, acc.w);
}

template <int RES>
__device__ __forceinline__ void trilerp_acc(const float4* __restrict__ cb,
                                            float x, float y, float z,
                                            float4& acc) {
    const float s = (float)(RES - 1);
    float fx = x * s, fy = y * s, fz = z * s;
    int x0 = min((int)fx, RES - 2);
    int y0 = min((int)fy, RES - 2);
    int z0 = min((int)fz, RES - 2);
    float tx = fx - (float)x0;
    float ty = fy - (float)y0;
    float tz = fz - (float)z0;

    int base = (x0 * RES + y0) * RES + z0;

    float4 c000 = cb[base];
    float4 c001 = cb[base + 1];
    float4 c010 = cb[base + RES];
    float4 c011 = cb[base + RES + 1];
    float4 c100 = cb[base + RES * RES];
    float4 c101 = cb[base + RES * RES + 1];
    float4 c110 = cb[base + RES * RES + RES];
    float4 c111 = cb[base + RES * RES + RES + 1];

    float wx0 = 1.0f - tx, wx1 = tx;
    float wy0 = 1.0f - ty, wy1 = ty;
    float wz0 = 1.0f - tz, wz1 = tz;

    fma4(acc, wx0 * wy0 * wz0, c000);
    fma4(acc, wx0 * wy0 * wz1, c001);
    fma4(acc, wx0 * wy1 * wz0, c010);
    fma4(acc, wx0 * wy1 * wz1, c011);
    fma4(acc, wx1 * wy0 * wz0, c100);
    fma4(acc, wx1 * wy0 * wz1, c101);
    fma4(acc, wx1 * wy1 * wz0, c110);
    fma4(acc, wx1 * wy1 * wz1, c111);
}

__device__ __forceinline__ void load_p01(const float* __restrict__ pts, int i,
                                         float& x, float& y, float& z, bool& inside) {
    float px = pts[3 * i + 0] * (1.0f / kSceneScale);
    float py = pts[3 * i + 1] * (1.0f / kSceneScale);
    float pz = pts[3 * i + 2] * (1.0f / kSceneScale);
    inside = (fabsf(px) < 0.5f) && (fabsf(py) < 0.5f) && (fabsf(pz) < 0.5f);
    x = fminf(fmaxf(px + 0.5f, 0.0f), 1.0f);
    y = fminf(fmaxf(py + 0.5f, 0.0f), 1.0f);
    z = fminf(fmaxf(pz + 0.5f, 0.0f), 1.0f);
}

__device__ __forceinline__ unsigned point_key(const float* __restrict__ pts, int i) {
    float x, y, z; bool inside;
    load_p01(pts, i, x, y, z, inside);
    if (!inside) return (unsigned)(kNBins - 1);
    int bx = min((int)(x * kG), kG - 1);
    int by = min((int)(y * kG), kG - 1);
    int bz = min((int)(z * kG), kG - 1);
    return (unsigned)((bx * kG + by) * kG + bz);
}

// ---------- Pass A: per-block LDS histogram, no global atomics ----------
__global__ __launch_bounds__(256) void keys_hist_kernel(
        const float* __restrict__ pts, unsigned* __restrict__ keys,
        unsigned* __restrict__ blockHist, int n, int chunk) {
    __shared__ unsigned hist[kNBins];
    int tid = threadIdx.x;
    for (int j = tid; j < kNBins; j += 256) hist[j] = 0;
    __syncthreads();
    int beg = blockIdx.x * chunk;
    int end = min(n, beg + chunk);
    for (int i = beg + tid; i < end; i += 256) {
        unsigned key = point_key(pts, i);
        keys[i] = key;
        atomicAdd(&hist[key], 1u);   // LDS atomic — fast
    }
    __syncthreads();
    // layout [bin][block] so a flat exclusive scan yields per-(block,bin) offsets
    for (int j = tid; j < kNBins; j += 256) blockHist[(size_t)j * kNB + blockIdx.x] = hist[j];
}

// ---------- Pass B1: scan 1024-element chunks ----------
__global__ __launch_bounds__(256) void scan_chunks_kernel(
        unsigned* __restrict__ data, unsigned* __restrict__ partials, int total) {
    __shared__ unsigned sums[256];
    int tid = threadIdx.x;
    int base = blockIdx.x * 1024 + tid * 4;
    uint4 v = make_uint4(0u, 0u, 0u, 0u);
    if (base + 3 < total) {
        v = *(const uint4*)(data + base);
    } else {
        unsigned* p = (unsigned*)&v;
        for (int k = 0; k < 4; ++k) if (base + k < total) p[k] = data[base + k];
    }
    unsigned s1 = v.x + v.y, s2 = s1 + v.z, s3 = s2 + v.w;
    sums[tid] = s3;
    __syncthreads();
    for (int off = 1; off < 256; off <<= 1) {
        unsigned t = (tid >= off) ? sums[tid - off] : 0u;
        __syncthreads();
        sums[tid] += t;
        __syncthreads();
    }
    unsigned excl = sums[tid] - s3;   // exclusive prefix of this thread's 4
    uint4 o;
    o.x = excl; o.y = excl + v.x; o.z = excl + s1; o.w = excl + s2;
    if (base + 3 < total) {
        *(uint4*)(data + base) = o;
    } else {
        unsigned* p = (unsigned*)&o;
        for (int k = 0; k < 4; ++k) if (base + k < total) data[base + k] = p[k];
    }
    if (tid == 255) partials[blockIdx.x] = sums[255];
}

// ---------- Pass B2: scan partials (1 block) ----------
__global__ __launch_bounds__(256) void scan_partials_kernel(unsigned* __restrict__ partials, int m) {
    __shared__ unsigned buf[256];
    __shared__ unsigned carry_s;
    int tid = threadIdx.x;
    if (tid == 0) carry_s = 0u;
    __syncthreads();
    for (int base = 0; base < m; base += 256) {
        unsigned v = (base + tid < m) ? partials[base + tid] : 0u;
        buf[tid] = v;
        __syncthreads();
        for (int off = 1; off < 256; off <<= 1) {
            unsigned t = (tid >= off) ? buf[tid - off] : 0u;
            __syncthreads();
            buf[tid] += t;
            __syncthreads();
        }
        unsigned incl = buf[tid];
        unsigned c = carry_s;
        if (base + tid < m) partials[base + tid] = c + incl - v;  // exclusive
        __syncthreads();
        if (tid == 255) carry_s = c + incl;
        __syncthreads();
    }
}

// ---------- Pass B3: add chunk offsets back ----------
__global__ __launch_bounds__(256) void scan_add_kernel(
        unsigned* __restrict__ data, const unsigned* __restrict__ partials, int total) {
    int tid = threadIdx.x;
    int base = blockIdx.x * 1024 + tid * 4;
    unsigned p = partials[blockIdx.x];
    if (base + 3 < total) {
        uint4 v = *(const uint4*)(data + base);
        v.x += p; v.y += p; v.z += p; v.w += p;
        *(uint4*)(data + base) = v;
    } else {
        for (int k = 0; k < 4; ++k) if (base + k < total) data[base + k] += p;
    }
}

// ---------- Pass C: scatter via LDS offsets (LDS atomics only) ----------
__global__ __launch_bounds__(256) void scatter_kernel(
        const unsigned* __restrict__ keys, const unsigned* __restrict__ blockHist,
        unsigned* __restrict__ order, int n, int chunk) {
    __shared__ unsigned offs[kNBins];
    int tid = threadIdx.x;
    for (int j = tid; j < kNBins; j += 256) offs[j] = blockHist[(size_t)j * kNB + blockIdx.x];
    __syncthreads();
    int beg = blockIdx.x * chunk;
    int end = min(n, beg + chunk);
    for (int i = beg + tid; i < end; i += 256) {
        unsigned k = keys[i];
        unsigned pos = atomicAdd(&offs[k], 1u);
        order[pos] = (unsigned)i;
    }
}

// ---------- Pass D: sorted-order gather + trilerp ----------
__global__ __launch_bounds__(256) void compute_kernel(
        const float* __restrict__ pts,
        const unsigned* __restrict__ order,
        const float4* __restrict__ cb0,
        const float4* __restrict__ cb1,
        const float4* __restrict__ cb2,
        const float4* __restrict__ cb3,
        const float4* __restrict__ cb4,
        float* __restrict__ out,
        int n) {
    int t = blockIdx.x * blockDim.x + threadIdx.x;
    if (t >= n) return;
    int i = (int)order[t];

    float x, y, z; bool inside;
    load_p01(pts, i, x, y, z, inside);

    float c0 = 0.0f, c1 = 0.0f, c2 = 0.0f, sg = 0.0f;
    if (inside) {
        float4 acc = make_float4(0.0f, 0.0f, 0.0f, 0.0f);
        trilerp_acc<16>(cb0, x, y, z, acc);
        trilerp_acc<32>(cb1, x, y, z, acc);
        trilerp_acc<64>(cb2, x, y, z, acc);
        trilerp_acc<128>(cb3, x, y, z, acc);
        trilerp_acc<256>(cb4, x, y, z, acc);
        c0 = acc.x; c1 = acc.y; c2 = acc.z; sg = expf(acc.w);
    }

    out[3 * i + 0] = c0;
    out[3 * i + 1] = c1;
    out[3 * i + 2] = c2;
    out[(size_t)3 * n + i] = sg;
}

// ---------- Fallback: direct kernel ----------
__global__ __launch_bounds__(256) void direct_kernel(
        const float* __restrict__ pts,
        const float4* __restrict__ cb0,
        const float4* __restrict__ cb1,
        const float4* __restrict__ cb2,
        const float4* __restrict__ cb3,
        const float4* __restrict__ cb4,
        float* __restrict__ out,
        int n) {
    int i = blockIdx.x * blockDim.x + threadIdx.x;
    if (i >= n) return;
    float x, y, z; bool inside;
    load_p01(pts, i, x, y, z, inside);
    float c0 = 0.0f, c1 = 0.0f, c2 = 0.0f, sg = 0.0f;
    if (inside) {
        float4 acc = make_float4(0.0f, 0.0f, 0.0f, 0.0f);
        trilerp_acc<16>(cb0, x, y, z, acc);
        trilerp_acc<32>(cb1, x, y, z, acc);
        trilerp_acc<64>(cb2, x, y, z, acc);
        trilerp_acc<128>(cb3, x, y, z, acc);
        trilerp_acc<256>(cb4, x, y, z, acc);
        c0 = acc.x; c1 = acc.y; c2 = acc.z; sg = expf(acc.w);
    }
    out[3 * i + 0] = c0;
    out[3 * i + 1] = c1;
    out[3 * i + 2] = c2;
    out[(size_t)3 * n + i] = sg;
}

extern "C" void kernel_launch(void* const* d_in, const int* in_sizes, int n_in,
                              void* d_out, int out_size, void* d_ws, size_t ws_size,
                              hipStream_t stream) {
    const float* pts = (const float*)d_in[0];
    const float4* cb0 = (const float4*)d_in[2];
    const float4* cb1 = (const float4*)d_in[3];
    const float4* cb2 = (const float4*)d_in[4];
    const float4* cb3 = (const float4*)d_in[5];
    const float4* cb4 = (const float4*)d_in[6];
    float* out = (float*)d_out;

    int n = in_sizes[0] / 3;

    const int histTotal = kNBins * kNB;                      // 1,048,832
    const int nChunks   = (histTotal + 1023) / 1024;         // 1025

    size_t off_keys  = 0;
    size_t off_order = off_keys + (size_t)n * 4;
    size_t off_hist  = off_order + (size_t)n * 4;
    size_t off_part  = off_hist + (size_t)histTotal * 4;
    size_t need      = off_part + (size_t)nChunks * 4;

    dim3 block(256);
    dim3 gridN((n + 255) / 256);

    if (ws_size < need) {
        direct_kernel<<<gridN, block, 0, stream>>>(pts, cb0, cb1, cb2, cb3, cb4, out, n);
        return;
    }

    unsigned* keys      = (unsigned*)((char*)d_ws + off_keys);
    unsigned* order     = (unsigned*)((char*)d_ws + off_order);
    unsigned* blockHist = (unsigned*)((char*)d_ws + off_hist);
    unsigned* partials  = (unsigned*)((char*)d_ws + off_part);

    int chunk = (n + kNB - 1) / kNB;

    keys_hist_kernel<<<dim3(kNB), block, 0, stream>>>(pts, keys, blockHist, n, chunk);
    scan_chunks_kernel<<<dim3(nChunks), block, 0, stream>>>(blockHist, partials, histTotal);
    scan_partials_kernel<<<dim3(1), block, 0, stream>>>(partials, nChunks);
    scan_add_kernel<<<dim3(nChunks), block, 0, stream>>>(blockHist, partials, histTotal);
    scatter_kernel<<<dim3(kNB), block, 0, stream>>>(keys, blockHist, order, n, chunk);
    compute_kernel<<<gridN, block, 0, stream>>>(pts, order, cb0, cb1, cb2, cb3, cb4, out, n);
}